// Round 7
// baseline (2443.361 us; speedup 1.0000x reference)
//
#include <hip/hip_runtime.h>
#include <math.h>

#define Bsz 64
#define Nn  512
#define Dd  128
#define NITER 100
#define SL8 8          // slices per batch
#define RS  64         // rows per slice

// ---------------- ws layout (bytes) ----------------
// M       : [64][512][512] f32 @ 0          (67108864)
// partials: [64][2][8][512] f32 @ 67108864  (2097152)  parity-double-buffered
// bar     : [64][32] u32 @ 69206016         (8192)
// sq1     : [64][512] f32 @ 69214208
// sq2     : [64][512] f32 @ 69345280
// rowmin  : [64][512] f32-bits @ 69476352
// maxm    : [64] f32-bits @ 69607424
// acc     : double @ 69607680

__device__ inline float blo(unsigned x) { return __uint_as_float(x << 16); }
__device__ inline float bhi(unsigned x) { return __uint_as_float(x & 0xffff0000u); }
__device__ inline unsigned short bf16rne(float f) {
    unsigned u = __float_as_uint(f);
    u += 0x7fffu + ((u >> 16) & 1u);
    return (unsigned short)(u >> 16);
}

// ---------------- init ----------------
__global__ void k_init(unsigned* __restrict__ rowmin, unsigned* __restrict__ maxm,
                       unsigned* __restrict__ bar, double* __restrict__ acc) {
    int t = blockIdx.x * blockDim.x + threadIdx.x;
    if (t < Bsz * Nn) rowmin[t] = 0x7F800000u;  // +inf
    if (t < Bsz) maxm[t] = 0u;
    if (t < Bsz * 32) bar[t] = 0u;
    if (t == 0) *acc = 0.0;
}

// ---------------- row squared norms ----------------
__global__ void k_norms(const float* __restrict__ x1, const float* __restrict__ x2,
                        float* __restrict__ sq1, float* __restrict__ sq2) {
    int gw = (blockIdx.x * blockDim.x + threadIdx.x) >> 6;
    int l = threadIdx.x & 63;
    bool first = gw < Bsz * Nn;
    int row = first ? gw : gw - Bsz * Nn;
    const float* src = first ? x1 : x2;
    float a = src[(size_t)row * Dd + l];
    float c = src[(size_t)row * Dd + 64 + l];
    float s = a * a + c * c;
    #pragma unroll
    for (int m = 32; m >= 1; m >>= 1) s += __shfl_xor(s, m);
    if (l == 0) (first ? sq1 : sq2)[row] = s;
}

// ---------------- M = pairwise distances + per-row min + per-batch max ----------------
__global__ __launch_bounds__(256) void k_gemm(
        const float* __restrict__ x1, const float* __restrict__ x2,
        const float* __restrict__ sq1, const float* __restrict__ sq2,
        float* __restrict__ M, unsigned* __restrict__ rowmin,
        unsigned* __restrict__ maxm) {
    __shared__ float As[64][129];
    __shared__ float Bs[64][129];
    __shared__ float redmin[64][16];
    __shared__ float wmax[4];
    const int b = blockIdx.z;
    const int i0 = blockIdx.y * 64, j0 = blockIdx.x * 64;
    const int tx = threadIdx.x, ty = threadIdx.y;
    const int tid = ty * 16 + tx;

    const float4* a4 = (const float4*)(x1 + ((size_t)b * Nn + i0) * Dd);
    const float4* b4 = (const float4*)(x2 + ((size_t)b * Nn + j0) * Dd);
    #pragma unroll
    for (int e = 0; e < 8; e++) {
        int idx = tid + e * 256;
        int r = idx >> 5, c = idx & 31;
        float4 va = a4[(size_t)r * 32 + c];
        float4 vb = b4[(size_t)r * 32 + c];
        As[r][c*4+0] = va.x; As[r][c*4+1] = va.y; As[r][c*4+2] = va.z; As[r][c*4+3] = va.w;
        Bs[r][c*4+0] = vb.x; Bs[r][c*4+1] = vb.y; Bs[r][c*4+2] = vb.z; Bs[r][c*4+3] = vb.w;
    }
    __syncthreads();

    float acc[4][4] = {{0.0f}};
    for (int k = 0; k < Dd; k++) {
        float av[4], bv[4];
        #pragma unroll
        for (int e = 0; e < 4; e++) av[e] = As[ty*4+e][k];
        #pragma unroll
        for (int f = 0; f < 4; f++) bv[f] = Bs[tx*4+f][k];
        #pragma unroll
        for (int e = 0; e < 4; e++)
            #pragma unroll
            for (int f = 0; f < 4; f++)
                acc[e][f] += av[e] * bv[f];
    }

    float lmax = 0.0f;
    #pragma unroll
    for (int e = 0; e < 4; e++) {
        const int i = i0 + ty*4 + e;
        const float s1 = sq1[b*Nn + i];
        float lmin = 3.0e38f;
        float mvv[4];
        #pragma unroll
        for (int f = 0; f < 4; f++) {
            const int j = j0 + tx*4 + f;
            float d2 = s1 + sq2[b*Nn + j] - 2.0f * acc[e][f];
            float m = sqrtf(fmaxf(d2, 0.0f));
            mvv[f] = m;
            lmin = fminf(lmin, m);
            lmax = fmaxf(lmax, m);
        }
        float4 mv; mv.x = mvv[0]; mv.y = mvv[1]; mv.z = mvv[2]; mv.w = mvv[3];
        *(float4*)(M + ((size_t)b * Nn + i) * Nn + j0 + tx*4) = mv;
        redmin[ty*4+e][tx] = lmin;
    }
    #pragma unroll
    for (int m = 32; m >= 1; m >>= 1) lmax = fmaxf(lmax, __shfl_xor(lmax, m));
    if ((tid & 63) == 0) wmax[tid >> 6] = lmax;
    __syncthreads();
    if (tid < 64) {
        float mn = redmin[tid][0];
        #pragma unroll
        for (int q = 1; q < 16; q++) mn = fminf(mn, redmin[tid][q]);
        atomicMin(&rowmin[b*Nn + i0 + tid], __float_as_uint(mn));
    }
    if (tid == 0) {
        float mm = fmaxf(fmaxf(wmax[0], wmax[1]), fmaxf(wmax[2], wmax[3]));
        atomicMax(&maxm[b], __float_as_uint(mm));
    }
}

// KtU over 64-row slice: wave w -> rows (w&3)+4k, col pair at cq*128 + l*2
__device__ inline void ktu_phase(const char* KsB_, const float* ush, float* colsum,
                                 int rw4, int cq, int l) {
    const int cb = cq * 256 + l * 4;
    float a0 = 0.f, a1 = 0.f;
    #pragma unroll
    for (int k2 = 0; k2 < 16; ++k2) {
        const int r = rw4 + 4 * k2;
        const unsigned kb = *(const unsigned*)(KsB_ + r * 1024 + (cb ^ ((r & 7) << 4)));
        const float ui = ush[r];
        a0 += blo(kb) * ui;
        a1 += bhi(kb) * ui;
    }
    atomicAdd(&colsum[cq * 128 + l * 2],     a0);
    atomicAdd(&colsum[cq * 128 + l * 2 + 1], a1);
}

// KV over 64-row slice: wave w -> cols [w*32,w*32+32), lane l -> row l
__device__ inline void kv_phase(const char* KsB_, const float* vsh, float* kvsum,
                                int w, int l) {
    float4 vv[8];
    #pragma unroll
    for (int q = 0; q < 8; ++q) vv[q] = *(const float4*)&vsh[w * 32 + q * 4];
    const int rsw = (l & 7) << 4;
    float d = 0.f;
    #pragma unroll
    for (int k = 0; k < 4; ++k) {
        const uint4 kb = *(const uint4*)(KsB_ + l * 1024 + ((w * 64 + k * 16) ^ rsw));
        const float4 va = vv[2 * k], vb4 = vv[2 * k + 1];
        d += blo(kb.x) * va.x  + bhi(kb.x) * va.y  + blo(kb.y) * va.z  + bhi(kb.y) * va.w
           + blo(kb.z) * vb4.x + bhi(kb.z) * vb4.y + blo(kb.w) * vb4.z + bhi(kb.w) * vb4.w;
    }
    atomicAdd(&kvsum[l], d);
}

// ---------------- persistent Sinkhorn: 2 batches/block (A/B pipelined), 8 slices/batch ----------------
__global__ __launch_bounds__(1024) void k_sink(
        const float* __restrict__ Mg, const float* __restrict__ rowmin_f,
        const float* __restrict__ maxm, float* __restrict__ part,
        unsigned* __restrict__ bar, double* __restrict__ acc) {
    __shared__ __align__(16) unsigned short KsA[RS * Nn];   // 65536 B bf16 swizzled
    __shared__ __align__(16) unsigned short KsB[RS * Nn];   // 65536 B
    __shared__ float colsumA[Nn], colsumB[Nn];              // 4096 B (zero-after-read)
    __shared__ float kvsumA[RS], kvsumB[RS];                // 512 B
    __shared__ float vshA[Nn], vshB[Nn];                    // 4096 B
    __shared__ float ushA[RS], ushB[RS];                    // 512 B
    __shared__ float rmlA[RS], rmlB[RS];                    // 512 B
    __shared__ float sred[16];
    __shared__ double dred[16];
    __shared__ float rminAs, rminBs;

    const int pr = blockIdx.x >> 3;       // batch pair
    const int s  = blockIdx.x & 7;        // slice
    const int A  = 2 * pr, Bb = 2 * pr + 1;
    const int r0 = s * RS;
    const int t  = threadIdx.x;           // 0..1023
    const int w  = t >> 6, l = t & 63;
    const char* KsAb = (const char*)KsA;
    const char* KsBbb = (const char*)KsB;
    const float inv512 = 1.0f / 512.0f;
    const float scA = 1.0f / (0.01f * maxm[A]);
    const float scB = 1.0f / (0.01f * maxm[Bb]);
    float* partA = part + (size_t)A  * (2 * SL8 * Nn);
    float* partB = part + (size_t)Bb * (2 * SL8 * Nn);
    unsigned* barA = bar + A * 32;
    unsigned* barB = bar + Bb * 32;

    // ---- setup: batch mins, zeros, u0, K fill
    {
        const int bx = (t < 512) ? A : Bb;
        float rv = rowmin_f[bx * Nn + (t & 511)];
        #pragma unroll
        for (int m = 32; m >= 1; m >>= 1) rv = fminf(rv, __shfl_xor(rv, m));
        if (l == 0) sred[w] = rv;
    }
    if (t < 512) { colsumA[t] = 0.f; colsumB[t] = 0.f; }
    if (t < RS) {
        kvsumA[t] = 0.f; kvsumB[t] = 0.f;
        rmlA[t] = rowmin_f[A  * Nn + r0 + t];
        rmlB[t] = rowmin_f[Bb * Nn + r0 + t];
    }
    __syncthreads();
    if (t == 0) {
        float qa = sred[0], qb = sred[8];
        #pragma unroll
        for (int i = 1; i < 8; ++i) { qa = fminf(qa, sred[i]); qb = fminf(qb, sred[8 + i]); }
        rminAs = qa; rminBs = qb;
    }
    __syncthreads();
    if (t < RS) {
        ushA[t] = __expf(-(rmlA[t] - rminAs) * scA) * inv512;
        ushB[t] = __expf(-(rmlB[t] - rminBs) * scB) * inv512;
    }
    // fill KsA, KsB (swizzled bf16 of exp(-(M - rowmin_row)*sc))
    for (int e = 0; e < 8; ++e) {
        const int chunk = e * 1024 + t;     // 0..8191
        const int row = chunk >> 7;
        const int c8  = chunk & 127;
        const float4 mA = *(const float4*)(Mg + ((size_t)(A * Nn + r0 + row)) * Nn + c8 * 4);
        const float4 mB = *(const float4*)(Mg + ((size_t)(Bb * Nn + r0 + row)) * Nn + c8 * 4);
        const float ra = rmlA[row], rb = rmlB[row];
        ushort4 pa, pb;
        pa.x = bf16rne(__expf(-(mA.x - ra) * scA));
        pa.y = bf16rne(__expf(-(mA.y - ra) * scA));
        pa.z = bf16rne(__expf(-(mA.z - ra) * scA));
        pa.w = bf16rne(__expf(-(mA.w - ra) * scA));
        pb.x = bf16rne(__expf(-(mB.x - rb) * scB));
        pb.y = bf16rne(__expf(-(mB.y - rb) * scB));
        pb.z = bf16rne(__expf(-(mB.z - rb) * scB));
        pb.w = bf16rne(__expf(-(mB.w - rb) * scB));
        const int off = row * 1024 + ((c8 * 8) ^ ((row & 7) << 4));
        *(ushort4*)((char*)KsA + off) = pa;
        *(ushort4*)((char*)KsB + off) = pb;
    }
    __syncthreads();

    const int rw4 = w & 3, cq = w >> 2;

    int par = 0;
    for (int it = 0; it < NITER; ++it) {
        const unsigned tgt = (unsigned)(SL8 * (it + 1));
        // P1: [deferred ushB update] + KtU_A
        if (it > 0 && t < RS) { ushB[t] = inv512 / kvsumB[t]; kvsumB[t] = 0.f; }
        ktu_phase(KsAb, ushA, colsumA, rw4, cq, l);
        __syncthreads();
        // P2: flush A partials + KtU_B
        if (t < 512) {
            float cs = colsumA[t]; colsumA[t] = 0.f;
            __hip_atomic_store(&partA[par * (SL8 * Nn) + s * Nn + t], cs,
                               __ATOMIC_RELAXED, __HIP_MEMORY_SCOPE_AGENT);
        }
        ktu_phase(KsBbb, ushB, colsumB, rw4, cq, l);
        __syncthreads();
        // P3: flush B partials + signal A
        if (t < 512) {
            float cs = colsumB[t]; colsumB[t] = 0.f;
            __hip_atomic_store(&partB[par * (SL8 * Nn) + s * Nn + t], cs,
                               __ATOMIC_RELAXED, __HIP_MEMORY_SCOPE_AGENT);
        }
        if (t == 0)
            __hip_atomic_fetch_add(barA, 1u, __ATOMIC_ACQ_REL, __HIP_MEMORY_SCOPE_AGENT);
        __syncthreads();
        // P4: signal B + spin A
        if (t == 0) {
            __hip_atomic_fetch_add(barB, 1u, __ATOMIC_ACQ_REL, __HIP_MEMORY_SCOPE_AGENT);
            while (__hip_atomic_load(barA, __ATOMIC_ACQUIRE, __HIP_MEMORY_SCOPE_AGENT) < tgt)
                __builtin_amdgcn_s_sleep(1);
        }
        __syncthreads();
        // P5: load A partials (flies during spin B) + spin B + vA
        {
            float pa[8];
            if (t < 512) {
                const float* pp = partA + par * (SL8 * Nn);
                #pragma unroll
                for (int q = 0; q < 8; ++q)
                    pa[q] = __hip_atomic_load(&pp[q * Nn + t], __ATOMIC_RELAXED,
                                              __HIP_MEMORY_SCOPE_AGENT);
            }
            if (t == 0) {
                while (__hip_atomic_load(barB, __ATOMIC_ACQUIRE, __HIP_MEMORY_SCOPE_AGENT) < tgt)
                    __builtin_amdgcn_s_sleep(1);
            }
            if (t < 512) {
                float ss = ((pa[0] + pa[1]) + (pa[2] + pa[3]))
                         + ((pa[4] + pa[5]) + (pa[6] + pa[7]));
                vshA[t] = inv512 / ss;
            }
        }
        __syncthreads();
        // P6: issue B partial loads + KV_A
        float pb[8];
        if (t < 512) {
            const float* pp = partB + par * (SL8 * Nn);
            #pragma unroll
            for (int q = 0; q < 8; ++q)
                pb[q] = __hip_atomic_load(&pp[q * Nn + t], __ATOMIC_RELAXED,
                                          __HIP_MEMORY_SCOPE_AGENT);
        }
        kv_phase(KsAb, vshA, kvsumA, w, l);
        __syncthreads();
        // P7: uA update + vB
        if (t < RS) { ushA[t] = inv512 / kvsumA[t]; kvsumA[t] = 0.f; }
        if (t < 512) {
            float ss = ((pb[0] + pb[1]) + (pb[2] + pb[3]))
                     + ((pb[4] + pb[5]) + (pb[6] + pb[7]));
            vshB[t] = inv512 / ss;
        }
        __syncthreads();
        // P8: KV_B
        kv_phase(KsBbb, vshB, kvsumB, w, l);
        __syncthreads();
        par ^= 1;
    }
    // epilogue: final uB
    if (t < RS) ushB[t] = inv512 / kvsumB[t];
    __syncthreads();

    // ---- cost: sum over local rows of u_i * sum_j M_ij K'_ij v_j  (both batches)
    double lacc = 0.0;
    {
        const int cb = cq * 256 + l * 4;
        const int j0 = cq * 128 + l * 2;
        #pragma unroll 4
        for (int k2 = 0; k2 < 16; ++k2) {
            const int r = rw4 + 4 * k2;
            const int ko = r * 1024 + (cb ^ ((r & 7) << 4));
            const unsigned ka = *(const unsigned*)(KsAb + ko);
            const unsigned kbq = *(const unsigned*)(KsBbb + ko);
            const float2 ma = *(const float2*)(Mg + ((size_t)(A  * Nn + r0 + r)) * Nn + j0);
            const float2 mb = *(const float2*)(Mg + ((size_t)(Bb * Nn + r0 + r)) * Nn + j0);
            float p = ma.x * blo(ka) * vshA[j0] + ma.y * bhi(ka) * vshA[j0 + 1];
            float q = mb.x * blo(kbq) * vshB[j0] + mb.y * bhi(kbq) * vshB[j0 + 1];
            lacc += (double)(p * ushA[r]) + (double)(q * ushB[r]);
        }
    }
    #pragma unroll
    for (int m = 32; m >= 1; m >>= 1) lacc += __shfl_xor(lacc, m);
    if (l == 0) dred[w] = lacc;
    __syncthreads();
    if (t == 0) {
        double tot = 0.0;
        #pragma unroll
        for (int q = 0; q < 16; ++q) tot += dred[q];
        atomicAdd(acc, tot);
    }
}

__global__ void k_final(const double* __restrict__ acc, float* __restrict__ out) {
    out[0] = (float)acc[0];
}

extern "C" void kernel_launch(void* const* d_in, const int* in_sizes, int n_in,
                              void* d_out, int out_size, void* d_ws, size_t ws_size,
                              hipStream_t stream) {
    const float* x1 = (const float*)d_in[0];
    const float* x2 = (const float*)d_in[1];
    float* out = (float*)d_out;
    char* ws = (char*)d_ws;

    float*    M      = (float*)(ws);
    float*    part   = (float*)(ws + 67108864);
    unsigned* bar    = (unsigned*)(ws + 69206016);
    float*    sq1    = (float*)(ws + 69214208);
    float*    sq2    = (float*)(ws + 69345280);
    float*    rowmin = (float*)(ws + 69476352);
    float*    maxm   = (float*)(ws + 69607424);
    double*   acc    = (double*)(ws + 69607680);

    hipLaunchKernelGGL(k_init, dim3(128), dim3(256), 0, stream,
                       (unsigned*)rowmin, (unsigned*)maxm, bar, acc);
    hipLaunchKernelGGL(k_norms, dim3(16384), dim3(256), 0, stream, x1, x2, sq1, sq2);
    hipLaunchKernelGGL(k_gemm, dim3(8, 8, 64), dim3(16, 16), 0, stream,
                       x1, x2, sq1, sq2, M, (unsigned*)rowmin, (unsigned*)maxm);
    hipLaunchKernelGGL(k_sink, dim3(256), dim3(1024), 0, stream,
                       M, rowmin, maxm, part, bar, acc);
    hipLaunchKernelGGL(k_final, dim3(1), dim3(1), 0, stream, acc, out);
}